// Round 2
// baseline (6782.285 us; speedup 1.0000x reference)
//
#include <hip/hip_runtime.h>
#include <hip/hip_bf16.h>
#include <math.h>

// ---------------- problem constants ----------------
#define NB      64          // 2*N_EP batches
#define S_LEN   1024
#define IN_DIM  255
#define D_IN    256         // IN_DIM + T_DIM
#define L_DIM   512
#define K_CLS   10
#define BCH     8           // batches per score chunk

#define TILE 64
#define BKK  16

typedef __hip_bfloat16 bf16;

__device__ __forceinline__ float u2f(unsigned short u) {
    return __uint_as_float(((unsigned int)u) << 16);
}
__device__ __forceinline__ unsigned short f2bu(float x) {
    bf16 b = __float2bfloat16(x);
    return *reinterpret_cast<unsigned short*>(&b);
}

// ---------------- build concatenated X (bf16) ----------------
__global__ __launch_bounds__(256) void build_xb(const float* __restrict__ xs,
                                                const float* __restrict__ ys,
                                                bf16* __restrict__ X) {
    long i = (long)blockIdx.x * 256 + threadIdx.x;          // over 65536*256
    long m = i >> 8;
    int  kk = (int)(i & 255);
    float v = (kk < IN_DIM) ? xs[m * IN_DIM + kk] : ys[m];
    X[i] = __float2bfloat16(v);
}

// ---------------- generic tiled GEMM, fp32 accumulate ----------------
// C[M,N] = alpha * A[M,K] @ op(B) (+bias) (relu). TA/TB/TC in {float, bf16}.
// TRANSB=false: B is K x N. TRANSB=true: B is N x K (C = A @ B^T).
template <typename TA, typename TB, typename TC, bool TRANSB, bool RELU, bool HASBIAS>
__global__ __launch_bounds__(256) void gemm(const TA* __restrict__ A,
                                            const TB* __restrict__ B,
                                            const float* __restrict__ bias,
                                            TC* __restrict__ C,
                                            int M, int N, int K,
                                            long sA, long sB, long sC,
                                            float alpha) {
    __shared__ float As[BKK][TILE + 1];
    __shared__ float Bs[BKK][TILE + 1];
    const int b = blockIdx.z;
    A += (long)b * sA;
    B += (long)b * sB;
    C += (long)b * sC;
    const int bm = blockIdx.y * TILE;
    const int bn = blockIdx.x * TILE;
    const int t  = threadIdx.x;
    const int tx = t & 15, ty = t >> 4;

    float acc[4][4] = {};

    for (int k0 = 0; k0 < K; k0 += BKK) {
        {   // A tile: 64 rows x 16 k, 4 contiguous k per thread
            int m  = t >> 2;
            int kq = (t & 3) * 4;
            const TA* src = A + (long)(bm + m) * K + k0 + kq;
            float a0, a1, a2, a3;
            if constexpr (sizeof(TA) == 2) {
                ushort4 uv = *(const ushort4*)src;
                a0 = u2f(uv.x); a1 = u2f(uv.y); a2 = u2f(uv.z); a3 = u2f(uv.w);
            } else {
                float4 fv = *(const float4*)src;
                a0 = fv.x; a1 = fv.y; a2 = fv.z; a3 = fv.w;
            }
            As[kq + 0][m] = a0; As[kq + 1][m] = a1;
            As[kq + 2][m] = a2; As[kq + 3][m] = a3;
        }
        if (!TRANSB) {   // B tile: 16 k x 64 n, 4 contiguous n per thread
            int k  = t >> 4;
            int nq = (t & 15) * 4;
            const TB* src = B + (long)(k0 + k) * N + bn + nq;
            float b0, b1, b2, b3;
            if constexpr (sizeof(TB) == 2) {
                ushort4 uv = *(const ushort4*)src;
                b0 = u2f(uv.x); b1 = u2f(uv.y); b2 = u2f(uv.z); b3 = u2f(uv.w);
            } else {
                float4 fv = *(const float4*)src;
                b0 = fv.x; b1 = fv.y; b2 = fv.z; b3 = fv.w;
            }
            Bs[k][nq + 0] = b0; Bs[k][nq + 1] = b1;
            Bs[k][nq + 2] = b2; Bs[k][nq + 3] = b3;
        } else {         // B tile from N x K: 64 n rows x 16 k
            int n  = t >> 2;
            int kq = (t & 3) * 4;
            const TB* src = B + (long)(bn + n) * K + k0 + kq;
            float b0, b1, b2, b3;
            if constexpr (sizeof(TB) == 2) {
                ushort4 uv = *(const ushort4*)src;
                b0 = u2f(uv.x); b1 = u2f(uv.y); b2 = u2f(uv.z); b3 = u2f(uv.w);
            } else {
                float4 fv = *(const float4*)src;
                b0 = fv.x; b1 = fv.y; b2 = fv.z; b3 = fv.w;
            }
            Bs[kq + 0][n] = b0; Bs[kq + 1][n] = b1;
            Bs[kq + 2][n] = b2; Bs[kq + 3][n] = b3;
        }
        __syncthreads();

        #pragma unroll
        for (int k = 0; k < BKK; ++k) {
            float a[4], bb[4];
            #pragma unroll
            for (int i = 0; i < 4; ++i) a[i] = As[k][ty * 4 + i];
            #pragma unroll
            for (int j = 0; j < 4; ++j) bb[j] = Bs[k][tx * 4 + j];
            #pragma unroll
            for (int i = 0; i < 4; ++i)
                #pragma unroll
                for (int j = 0; j < 4; ++j)
                    acc[i][j] = fmaf(a[i], bb[j], acc[i][j]);
        }
        __syncthreads();
    }

    #pragma unroll
    for (int i = 0; i < 4; ++i) {
        const int row  = bm + ty * 4 + i;
        const int col0 = bn + tx * 4;
        float v[4];
        #pragma unroll
        for (int j = 0; j < 4; ++j) {
            float x = acc[i][j] * alpha;
            if (HASBIAS) x += bias[col0 + j];
            if (RELU) x = fmaxf(x, 0.f);
            v[j] = x;
        }
        if constexpr (sizeof(TC) == 2) {
            ushort4 o; o.x = f2bu(v[0]); o.y = f2bu(v[1]); o.z = f2bu(v[2]); o.w = f2bu(v[3]);
            *(ushort4*)(C + (long)row * N + col0) = o;
        } else {
            float4 o; o.x = v[0]; o.y = v[1]; o.z = v[2]; o.w = v[3];
            *(float4*)(C + (long)row * N + col0) = o;
        }
    }
}

// ---------------- row softmax over 1024 bf16 cols, in place ----------------
__global__ __launch_bounds__(256) void softmax_rows_bf16(bf16* __restrict__ Sc) {
    bf16* p = Sc + (long)blockIdx.x * 1024;
    const int t = threadIdx.x;
    ushort4 uv = reinterpret_cast<ushort4*>(p)[t];
    float v0 = u2f(uv.x), v1 = u2f(uv.y), v2 = u2f(uv.z), v3 = u2f(uv.w);
    float m = fmaxf(fmaxf(v0, v1), fmaxf(v2, v3));
    #pragma unroll
    for (int o = 32; o > 0; o >>= 1) m = fmaxf(m, __shfl_xor(m, o, 64));
    __shared__ float redm[4];
    if ((t & 63) == 0) redm[t >> 6] = m;
    __syncthreads();
    m = fmaxf(fmaxf(redm[0], redm[1]), fmaxf(redm[2], redm[3]));

    float e0 = __expf(v0 - m), e1 = __expf(v1 - m);
    float e2 = __expf(v2 - m), e3 = __expf(v3 - m);
    float s = e0 + e1 + e2 + e3;
    #pragma unroll
    for (int o = 32; o > 0; o >>= 1) s += __shfl_xor(s, o, 64);
    __shared__ float reds[4];
    if ((t & 63) == 0) reds[t >> 6] = s;
    __syncthreads();
    s = reds[0] + reds[1] + reds[2] + reds[3];
    const float inv = 1.f / s;
    ushort4 o;
    o.x = f2bu(e0 * inv); o.y = f2bu(e1 * inv);
    o.z = f2bu(e2 * inv); o.w = f2bu(e3 * inv);
    reinterpret_cast<ushort4*>(p)[t] = o;
}

// ---------------- column sums of attn2 chunk ----------------
__global__ __launch_bounds__(256) void colsum_bf16(const bf16* __restrict__ Sc,
                                                   float* __restrict__ w, int c0) {
    const int b = blockIdx.y;                          // 0..BCH-1
    const int c = blockIdx.x * 256 + threadIdx.x;      // grid.x = 4
    const bf16* p = Sc + (long)b * (S_LEN * S_LEN) + c;
    float acc = 0.f;
    for (int q = 0; q < S_LEN; ++q) acc += __bfloat162float(p[(long)q * S_LEN]);
    w[(c0 * BCH + b) * S_LEN + c] = acc;
}

// ---------------- u = (w/S) @ h  (per batch) ----------------
__global__ __launch_bounds__(256) void pool_u(const bf16* __restrict__ h,
                                              const float* __restrict__ w,
                                              float* __restrict__ u) {
    const int b = blockIdx.x;           // 64 batches
    const int t = threadIdx.x;          // owns d = 2t, 2t+1
    __shared__ float wl[S_LEN];
    for (int i = t; i < S_LEN; i += 256) wl[i] = w[b * S_LEN + i];
    __syncthreads();
    const bf16* hp = h + (long)b * S_LEN * L_DIM;
    float a0 = 0.f, a1 = 0.f;
    for (int q = 0; q < S_LEN; ++q) {
        ushort2 uv = *(const ushort2*)(hp + (long)q * L_DIM + t * 2);
        float ww = wl[q];
        a0 = fmaf(ww, u2f(uv.x), a0);
        a1 = fmaf(ww, u2f(uv.y), a1);
    }
    u[b * L_DIM + t * 2 + 0] = a0 * (1.f / (float)S_LEN);
    u[b * L_DIM + t * 2 + 1] = a1 * (1.f / (float)S_LEN);
}

// ---------------- log_softmax over groups of 10 ----------------
__global__ __launch_bounds__(256) void log_softmax10(const float* __restrict__ logits,
                                                     float* __restrict__ out) {
    const int t = blockIdx.x * 256 + threadIdx.x;     // 64*512 groups
    if (t >= NB * L_DIM) return;
    const float* p = logits + (long)t * K_CLS;
    float v[K_CLS], m = -INFINITY;
    #pragma unroll
    for (int k = 0; k < K_CLS; ++k) { v[k] = p[k]; m = fmaxf(m, v[k]); }
    float s = 0.f;
    #pragma unroll
    for (int k = 0; k < K_CLS; ++k) s += __expf(v[k] - m);
    const float lse = m + logf(s);
    float* o = out + (long)t * K_CLS;
    #pragma unroll
    for (int k = 0; k < K_CLS; ++k) o[k] = v[k] - lse;
}

// ---------------- host launch ----------------
extern "C" void kernel_launch(void* const* d_in, const int* in_sizes, int n_in,
                              void* d_out, int out_size, void* d_ws, size_t ws_size,
                              hipStream_t stream) {
    const float* xs  = (const float*)d_in[0];
    const float* ys  = (const float*)d_in[1];
    const float* Wq1 = (const float*)d_in[2];  const float* bq1 = (const float*)d_in[3];
    const float* Wk1 = (const float*)d_in[4];  const float* bk1 = (const float*)d_in[5];
    const float* Wv1 = (const float*)d_in[6];  const float* bv1 = (const float*)d_in[7];
    const float* Wq2 = (const float*)d_in[8];  const float* bq2 = (const float*)d_in[9];
    const float* Wk2 = (const float*)d_in[10]; const float* bk2 = (const float*)d_in[11];
    const float* Wv2 = (const float*)d_in[12]; const float* bv2 = (const float*)d_in[13];
    const float* We  = (const float*)d_in[14]; const float* be  = (const float*)d_in[15];
    float* out = (float*)d_out;

    const long M  = (long)NB * S_LEN;        // 65536
    const long QL = M * L_DIM;               // 33.5M elems
    const long SL = (long)S_LEN * L_DIM;     // per-batch activation stride
    const long SS = (long)S_LEN * S_LEN;     // per-batch score stride

    // bf16 region (elems):                       bytes
    bf16* Xb  = (bf16*)d_ws;                 // 33.5 MB
    bf16* B1  = Xb + M * D_IN;               // 67.1 MB  (q1 -> h)
    bf16* B2  = B1 + QL;                     // 67.1 MB  (k1 -> q2)
    bf16* B3  = B2 + QL;                     // 67.1 MB  (v1 -> k2)
    bf16* Scb = B3 + QL;                     // 16.8 MB  (8-batch score chunk)
    // fp32 region:
    float* w   = (float*)(Scb + (long)BCH * SS);   // 65536
    float* u   = w   + M;                          // 32768
    float* phi = u   + NB * L_DIM;                 // 32768
    float* lg  = phi + NB * L_DIM;                 // 327680
    // total ~253.5 MB

    const float inv_sqrt_L = 0.044194173824159216f;  // 1/sqrt(512)

    // 0) X = concat(x_sets, y_sets) -> bf16
    build_xb<<<dim3((unsigned)(M * D_IN / 256)), 256, 0, stream>>>(xs, ys, Xb);

    // 1) layer-1 QKV  (65536 x 512, K=256):  q1->B1, k1->B2, v1->B3
    {
        dim3 g(L_DIM / TILE, (unsigned)(M / TILE), 1);
        gemm<bf16, float, bf16, false, false, true><<<g, 256, 0, stream>>>(Xb, Wq1, bq1, B1, (int)M, L_DIM, D_IN, 0, 0, 0, 1.f);
        gemm<bf16, float, bf16, false, false, true><<<g, 256, 0, stream>>>(Xb, Wk1, bk1, B2, (int)M, L_DIM, D_IN, 0, 0, 0, 1.f);
        gemm<bf16, float, bf16, false, false, true><<<g, 256, 0, stream>>>(Xb, Wv1, bv1, B3, (int)M, L_DIM, D_IN, 0, 0, 0, 1.f);
    }
    // 2) layer-1 attention, chunked: scores -> softmax -> h = relu(attn @ v1)
    //    h overwrites q1 (B1), chunk-local so ordering is safe.
    for (int c = 0; c < NB / BCH; ++c) {
        const long aoff = (long)c * BCH * SL;
        dim3 gs(S_LEN / TILE, S_LEN / TILE, BCH);
        gemm<bf16, bf16, bf16, true, false, false><<<gs, 256, 0, stream>>>(
            B1 + aoff, B2 + aoff, nullptr, Scb, S_LEN, S_LEN, L_DIM, SL, SL, SS, inv_sqrt_L);
        softmax_rows_bf16<<<dim3(BCH * S_LEN), 256, 0, stream>>>(Scb);
        dim3 gp(L_DIM / TILE, S_LEN / TILE, BCH);
        gemm<bf16, bf16, bf16, false, true, false><<<gp, 256, 0, stream>>>(
            Scb, B3 + aoff, nullptr, B1 + aoff, S_LEN, L_DIM, S_LEN, SS, SL, SL, 1.f);
    }
    // 3) layer-2 Q,K from h (B1):  q2->B2, k2->B3   (v2 eliminated by linearity)
    {
        dim3 g(L_DIM / TILE, (unsigned)(M / TILE), 1);
        gemm<bf16, float, bf16, false, false, true><<<g, 256, 0, stream>>>(B1, Wq2, bq2, B2, (int)M, L_DIM, L_DIM, 0, 0, 0, 1.f);
        gemm<bf16, float, bf16, false, false, true><<<g, 256, 0, stream>>>(B1, Wk2, bk2, B3, (int)M, L_DIM, L_DIM, 0, 0, 0, 1.f);
    }
    // 4) layer-2 attention, chunked: scores2 -> softmax -> w = colsum(attn2)
    for (int c = 0; c < NB / BCH; ++c) {
        const long aoff = (long)c * BCH * SL;
        dim3 gs(S_LEN / TILE, S_LEN / TILE, BCH);
        gemm<bf16, bf16, bf16, true, false, false><<<gs, 256, 0, stream>>>(
            B2 + aoff, B3 + aoff, nullptr, Scb, S_LEN, S_LEN, L_DIM, SL, SL, SS, inv_sqrt_L);
        softmax_rows_bf16<<<dim3(BCH * S_LEN), 256, 0, stream>>>(Scb);
        colsum_bf16<<<dim3(S_LEN / 256, BCH), 256, 0, stream>>>(Scb, w, c);
    }
    // 5) u = (w/S) @ h
    pool_u<<<dim3(NB), 256, 0, stream>>>(B1, w, u);
    // 6) phi = relu(u @ Wv2 + bv2)   (64 x 512, K=512)
    {
        dim3 g(L_DIM / TILE, 1, 1);
        gemm<float, float, float, false, true, true><<<g, 256, 0, stream>>>(u, Wv2, bv2, phi, NB, L_DIM, L_DIM, 0, 0, 0, 1.f);
    }
    // 7) logits = phi @ We + be   (64 x 5120, K=512)
    {
        dim3 g((L_DIM * K_CLS) / TILE, 1, 1);
        gemm<float, float, float, false, false, true><<<g, 256, 0, stream>>>(phi, We, be, lg, NB, L_DIM * K_CLS, L_DIM, 0, 0, 0, 1.f);
    }
    // 8) log_softmax over K=10
    log_softmax10<<<dim3((NB * L_DIM + 255) / 256), 256, 0, stream>>>(lg, out);
}

// Round 3
// 1367.169 us; speedup vs baseline: 4.9608x; 4.9608x over previous
//
#include <hip/hip_runtime.h>
#include <hip/hip_bf16.h>
#include <math.h>

// ---------------- problem constants ----------------
#define NB      64          // 2*N_EP batches
#define S_LEN   1024
#define IN_DIM  255
#define D_IN    256         // IN_DIM + T_DIM
#define L_DIM   512
#define K_CLS   10

#define TILE 64
#define BKK  16

typedef __hip_bfloat16 bf16;
typedef __attribute__((ext_vector_type(8))) short short8;
typedef __attribute__((ext_vector_type(4))) float f32x4;

__device__ __forceinline__ float u2f(unsigned short u) {
    return __uint_as_float(((unsigned int)u) << 16);
}
__device__ __forceinline__ unsigned short f2bu(float x) {
    bf16 b = __float2bfloat16(x);
    return *reinterpret_cast<unsigned short*>(&b);
}

// async global->LDS, 16B per lane; lds dest = wave-uniform base + lane*16
typedef const __attribute__((address_space(1))) unsigned int* gas_t;
typedef __attribute__((address_space(3))) unsigned int* las_t;
__device__ __forceinline__ void gload16(const bf16* g, bf16* l) {
    __builtin_amdgcn_global_load_lds((gas_t)(const void*)g, (las_t)(void*)l, 16, 0, 0);
}

// ---------------- build concatenated X (bf16) ----------------
__global__ __launch_bounds__(256) void build_xb(const float* __restrict__ xs,
                                                const float* __restrict__ ys,
                                                bf16* __restrict__ X) {
    long i = (long)blockIdx.x * 256 + threadIdx.x;          // over 65536*256
    long m = i >> 8;
    int  kk = (int)(i & 255);
    float v = (kk < IN_DIM) ? xs[m * IN_DIM + kk] : ys[m];
    X[i] = __float2bfloat16(v);
}

// ---------------- weight transpose fp32[K][N] -> bf16[N][K] ----------------
__global__ __launch_bounds__(256) void transpose_w(const float* __restrict__ W,
                                                   bf16* __restrict__ WT,
                                                   int K, int N) {
    int i = blockIdx.x * 256 + threadIdx.x;
    if (i >= K * N) return;
    int n = i / K, k = i - n * K;
    WT[i] = __float2bfloat16(W[(long)k * N + n]);
}

// ---------------- MFMA GEMM: C = alpha * A @ B^T (+bias) (relu) ----------------
// A: [M][K] bf16 row-major. B: [N][K] bf16 row-major. C bf16.
// TRANSC=false: C[row][col], leading dim ldc (=N). TRANSC=true: C[col][row], ldc (=M).
// Batched over blockIdx.z with element strides sA, sB, sC.
// 128x128 tile, 4 waves (each 64x64 = 4x4 frags of 16x16), BK=32.
template <bool TRANSC, bool RELU, bool HASBIAS>
__global__ __launch_bounds__(256) void gemm_mfma(const bf16* __restrict__ A,
                                                 const bf16* __restrict__ B,
                                                 const float* __restrict__ bias,
                                                 bf16* __restrict__ C,
                                                 int K, long sA, long sB, long sC,
                                                 int ldc, float alpha) {
    __shared__ bf16 As[128 * 32];
    __shared__ bf16 Bs[128 * 32];
    const int b = blockIdx.z;
    A += (long)b * sA;
    B += (long)b * sB;
    C += (long)b * sC;
    const int bm = blockIdx.y * 128;
    const int bn = blockIdx.x * 128;
    const int t  = threadIdx.x;
    const int ln = t & 63;
    const int wv = t >> 6;          // wave 0..3
    const int wm = wv >> 1;         // 2x2 wave grid over 128x128
    const int wn = wv & 1;

    // staging source: thread t covers row (t>>2) [+64 in round 2], k-chunk (t&3)*8
    const bf16* gA = A + (long)(bm + (t >> 2)) * K + (t & 3) * 8;
    const bf16* gB = B + (long)(bn + (t >> 2)) * K + (t & 3) * 8;
    bf16* lA = As + wv * 512;       // wave-uniform LDS base (1024 B per wave)
    bf16* lB = Bs + wv * 512;

    f32x4 acc[4][4];
    #pragma unroll
    for (int i = 0; i < 4; ++i)
        #pragma unroll
        for (int j = 0; j < 4; ++j)
            #pragma unroll
            for (int q = 0; q < 4; ++q) acc[i][j][q] = 0.f;

    const int ro = ln & 15;
    const int ko = (ln >> 4) * 8;

    for (int k0 = 0; k0 < K; k0 += 32) {
        gload16(gA + k0,            lA);
        gload16(gA + 64 * K + k0,   lA + 2048);
        gload16(gB + k0,            lB);
        gload16(gB + 64 * K + k0,   lB + 2048);
        __syncthreads();

        short8 af[4], bg[4];
        #pragma unroll
        for (int i = 0; i < 4; ++i) {
            af[i] = *(const short8*)(As + (wm * 64 + i * 16 + ro) * 32 + ko);
            bg[i] = *(const short8*)(Bs + (wn * 64 + i * 16 + ro) * 32 + ko);
        }
        #pragma unroll
        for (int i = 0; i < 4; ++i)
            #pragma unroll
            for (int j = 0; j < 4; ++j)
                acc[i][j] = __builtin_amdgcn_mfma_f32_16x16x32_bf16(af[i], bg[j], acc[i][j], 0, 0, 0);
        __syncthreads();
    }

    // C/D layout: col = lane&15, row = (lane>>4)*4 + reg
    const int r0 = bm + wm * 64 + (ln >> 4) * 4;
    const int c0 = bn + wn * 64 + (ln & 15);
    if constexpr (TRANSC) {
        #pragma unroll
        for (int i = 0; i < 4; ++i) {
            const int rowb = r0 + i * 16;
            #pragma unroll
            for (int j = 0; j < 4; ++j) {
                const int col = c0 + j * 16;
                const float bi = HASBIAS ? bias[col] : 0.f;
                ushort4 o;
                float v0 = acc[i][j][0] * alpha + bi;
                float v1 = acc[i][j][1] * alpha + bi;
                float v2 = acc[i][j][2] * alpha + bi;
                float v3 = acc[i][j][3] * alpha + bi;
                if (RELU) { v0 = fmaxf(v0, 0.f); v1 = fmaxf(v1, 0.f); v2 = fmaxf(v2, 0.f); v3 = fmaxf(v3, 0.f); }
                o.x = f2bu(v0); o.y = f2bu(v1); o.z = f2bu(v2); o.w = f2bu(v3);
                *(ushort4*)(C + (long)col * ldc + rowb) = o;
            }
        }
    } else {
        #pragma unroll
        for (int i = 0; i < 4; ++i) {
            #pragma unroll
            for (int j = 0; j < 4; ++j) {
                const int col = c0 + j * 16;
                const float bi = HASBIAS ? bias[col] : 0.f;
                #pragma unroll
                for (int q = 0; q < 4; ++q) {
                    float v = acc[i][j][q] * alpha + bi;
                    if (RELU) v = fmaxf(v, 0.f);
                    C[(long)(r0 + i * 16 + q) * ldc + col] = __float2bfloat16(v);
                }
            }
        }
    }
}

// ---------------- tiny fp32 tiled GEMM (tail, M=64) ----------------
template <bool RELU>
__global__ __launch_bounds__(256) void gemm_f32s(const float* __restrict__ A,
                                                 const float* __restrict__ B,
                                                 const float* __restrict__ bias,
                                                 float* __restrict__ C,
                                                 int M, int N, int K) {
    __shared__ float As[BKK][TILE + 1];
    __shared__ float Bs[BKK][TILE + 1];
    const int bm = blockIdx.y * TILE;
    const int bn = blockIdx.x * TILE;
    const int t  = threadIdx.x;
    const int tx = t & 15, ty = t >> 4;
    float acc[4][4] = {};
    for (int k0 = 0; k0 < K; k0 += BKK) {
        {
            int m  = t >> 2;
            int kq = (t & 3) * 4;
            const float4 av = *(const float4*)(A + (long)(bm + m) * K + k0 + kq);
            As[kq + 0][m] = av.x; As[kq + 1][m] = av.y;
            As[kq + 2][m] = av.z; As[kq + 3][m] = av.w;
        }
        {
            int k  = t >> 4;
            int nq = (t & 15) * 4;
            const float4 bv = *(const float4*)(B + (long)(k0 + k) * N + bn + nq);
            Bs[k][nq + 0] = bv.x; Bs[k][nq + 1] = bv.y;
            Bs[k][nq + 2] = bv.z; Bs[k][nq + 3] = bv.w;
        }
        __syncthreads();
        #pragma unroll
        for (int k = 0; k < BKK; ++k) {
            float a[4], bb[4];
            #pragma unroll
            for (int i = 0; i < 4; ++i) a[i] = As[k][ty * 4 + i];
            #pragma unroll
            for (int j = 0; j < 4; ++j) bb[j] = Bs[k][tx * 4 + j];
            #pragma unroll
            for (int i = 0; i < 4; ++i)
                #pragma unroll
                for (int j = 0; j < 4; ++j)
                    acc[i][j] = fmaf(a[i], bb[j], acc[i][j]);
        }
        __syncthreads();
    }
    #pragma unroll
    for (int i = 0; i < 4; ++i) {
        const int row  = bm + ty * 4 + i;
        const int col0 = bn + tx * 4;
        #pragma unroll
        for (int j = 0; j < 4; ++j) {
            float x = acc[i][j] + bias[col0 + j];
            if (RELU) x = fmaxf(x, 0.f);
            C[(long)row * N + col0 + j] = x;
        }
    }
}

// ---------------- row softmax over 1024 bf16 cols, in place ----------------
__global__ __launch_bounds__(256) void softmax_rows_bf16(bf16* __restrict__ Sc) {
    bf16* p = Sc + (long)blockIdx.x * 1024;
    const int t = threadIdx.x;
    ushort4 uv = reinterpret_cast<ushort4*>(p)[t];
    float v0 = u2f(uv.x), v1 = u2f(uv.y), v2 = u2f(uv.z), v3 = u2f(uv.w);
    float m = fmaxf(fmaxf(v0, v1), fmaxf(v2, v3));
    #pragma unroll
    for (int o = 32; o > 0; o >>= 1) m = fmaxf(m, __shfl_xor(m, o, 64));
    __shared__ float redm[4];
    if ((t & 63) == 0) redm[t >> 6] = m;
    __syncthreads();
    m = fmaxf(fmaxf(redm[0], redm[1]), fmaxf(redm[2], redm[3]));

    float e0 = __expf(v0 - m), e1 = __expf(v1 - m);
    float e2 = __expf(v2 - m), e3 = __expf(v3 - m);
    float s = e0 + e1 + e2 + e3;
    #pragma unroll
    for (int o = 32; o > 0; o >>= 1) s += __shfl_xor(s, o, 64);
    __shared__ float reds[4];
    if ((t & 63) == 0) reds[t >> 6] = s;
    __syncthreads();
    s = reds[0] + reds[1] + reds[2] + reds[3];
    const float inv = 1.f / s;
    ushort4 o;
    o.x = f2bu(e0 * inv); o.y = f2bu(e1 * inv);
    o.z = f2bu(e2 * inv); o.w = f2bu(e3 * inv);
    reinterpret_cast<ushort4*>(p)[t] = o;
}

// ---------------- column sums of attn2 chunk ----------------
__global__ __launch_bounds__(256) void colsum_bf16(const bf16* __restrict__ Sc,
                                                   float* __restrict__ w,
                                                   int c0, int bch) {
    const int b = blockIdx.y;                          // 0..bch-1
    const int c = blockIdx.x * 256 + threadIdx.x;      // grid.x = 4
    const bf16* p = Sc + (long)b * (S_LEN * S_LEN) + c;
    float acc = 0.f;
    for (int q = 0; q < S_LEN; ++q) acc += __bfloat162float(p[(long)q * S_LEN]);
    w[(c0 * bch + b) * S_LEN + c] = acc;
}

// ---------------- u = (w/S) @ h  (per batch) ----------------
__global__ __launch_bounds__(256) void pool_u(const bf16* __restrict__ h,
                                              const float* __restrict__ w,
                                              float* __restrict__ u) {
    const int b = blockIdx.x;           // 64 batches
    const int t = threadIdx.x;          // owns d = 2t, 2t+1
    __shared__ float wl[S_LEN];
    for (int i = t; i < S_LEN; i += 256) wl[i] = w[b * S_LEN + i];
    __syncthreads();
    const bf16* hp = h + (long)b * S_LEN * L_DIM;
    float a0 = 0.f, a1 = 0.f;
    for (int q = 0; q < S_LEN; ++q) {
        ushort2 uv = *(const ushort2*)(hp + (long)q * L_DIM + t * 2);
        float ww = wl[q];
        a0 = fmaf(ww, u2f(uv.x), a0);
        a1 = fmaf(ww, u2f(uv.y), a1);
    }
    u[b * L_DIM + t * 2 + 0] = a0 * (1.f / (float)S_LEN);
    u[b * L_DIM + t * 2 + 1] = a1 * (1.f / (float)S_LEN);
}

// ---------------- log_softmax over groups of 10 ----------------
__global__ __launch_bounds__(256) void log_softmax10(const float* __restrict__ logits,
                                                     float* __restrict__ out) {
    const int t = blockIdx.x * 256 + threadIdx.x;     // 64*512 groups
    if (t >= NB * L_DIM) return;
    const float* p = logits + (long)t * K_CLS;
    float v[K_CLS], m = -INFINITY;
    #pragma unroll
    for (int k = 0; k < K_CLS; ++k) { v[k] = p[k]; m = fmaxf(m, v[k]); }
    float s = 0.f;
    #pragma unroll
    for (int k = 0; k < K_CLS; ++k) s += __expf(v[k] - m);
    const float lse = m + logf(s);
    float* o = out + (long)t * K_CLS;
    #pragma unroll
    for (int k = 0; k < K_CLS; ++k) o[k] = v[k] - lse;
}

// ---------------- host launch ----------------
extern "C" void kernel_launch(void* const* d_in, const int* in_sizes, int n_in,
                              void* d_out, int out_size, void* d_ws, size_t ws_size,
                              hipStream_t stream) {
    const float* xs  = (const float*)d_in[0];
    const float* ys  = (const float*)d_in[1];
    const float* Wq1 = (const float*)d_in[2];  const float* bq1 = (const float*)d_in[3];
    const float* Wk1 = (const float*)d_in[4];  const float* bk1 = (const float*)d_in[5];
    const float* Wv1 = (const float*)d_in[6];  const float* bv1 = (const float*)d_in[7];
    const float* Wq2 = (const float*)d_in[8];  const float* bq2 = (const float*)d_in[9];
    const float* Wk2 = (const float*)d_in[10]; const float* bk2 = (const float*)d_in[11];
    const float* Wv2 = (const float*)d_in[12]; const float* bv2 = (const float*)d_in[13];
    const float* We  = (const float*)d_in[14]; const float* be  = (const float*)d_in[15];
    float* out = (float*)d_out;

    const long M  = (long)NB * S_LEN;        // 65536
    const long QL = M * L_DIM;               // 33.5M elems
    const long SL = (long)S_LEN * L_DIM;     // per-batch activation stride (also V1T stride)
    const long SS = (long)S_LEN * S_LEN;     // per-batch score stride

    // ---- workspace layout (bf16 first, then fp32) ----
    bf16* Xb  = (bf16*)d_ws;                 // 33.5 MB
    bf16* B1  = Xb + M * D_IN;               // 67.1 MB  (q1 -> h)
    bf16* B2  = B1 + QL;                     // 67.1 MB  (k1 -> q2)
    bf16* B3  = B2 + QL;                     // 67.1 MB  (v1T -> k2)
    bf16* WTb = B3 + QL;                     // 1.8 MB: Wq1T,Wk1T,Wv1T (512x256), Wq2T,Wk2T (512x512)
    bf16* Wq1T = WTb;
    bf16* Wk1T = Wq1T + L_DIM * D_IN;
    bf16* Wv1T = Wk1T + L_DIM * D_IN;
    bf16* Wq2T = Wv1T + L_DIM * D_IN;
    bf16* Wk2T = Wq2T + L_DIM * L_DIM;
    bf16* Scb  = Wk2T + L_DIM * L_DIM;       // BCH * 2 MB score chunk

    // adaptive chunk size by ws_size
    const size_t base_b = (size_t)((char*)Scb - (char*)d_ws);
    const size_t f32_b  = (size_t)(M + 2 * NB * L_DIM + NB * L_DIM * K_CLS) * 4 + 256;
    int BCH = 32;
    while (BCH > 8 && base_b + (size_t)BCH * SS * 2 + f32_b > ws_size) BCH >>= 1;

    float* w   = (float*)(Scb + (long)BCH * SS);
    float* u   = w   + M;
    float* phi = u   + NB * L_DIM;
    float* lg  = phi + NB * L_DIM;

    const float inv_sqrt_L = 0.044194173824159216f;  // 1/sqrt(512)

    // 0) X = concat(x_sets, y_sets) -> bf16 ; transpose weights -> bf16
    build_xb<<<dim3((unsigned)(M * D_IN / 256)), 256, 0, stream>>>(xs, ys, Xb);
    transpose_w<<<dim3(512), 256, 0, stream>>>(Wq1, Wq1T, D_IN, L_DIM);
    transpose_w<<<dim3(512), 256, 0, stream>>>(Wk1, Wk1T, D_IN, L_DIM);
    transpose_w<<<dim3(512), 256, 0, stream>>>(Wv1, Wv1T, D_IN, L_DIM);
    transpose_w<<<dim3(1024), 256, 0, stream>>>(Wq2, Wq2T, L_DIM, L_DIM);
    transpose_w<<<dim3(1024), 256, 0, stream>>>(Wk2, Wk2T, L_DIM, L_DIM);

    // 1) layer-1 QKV: q1->B1, k1->B2 (normal), v1->B3 TRANSPOSED per batch [512][1024]
    {
        dim3 g(L_DIM / 128, S_LEN / 128, NB);
        gemm_mfma<false, false, true><<<g, 256, 0, stream>>>(Xb, Wq1T, bq1, B1, D_IN, (long)S_LEN * D_IN, 0, SL, L_DIM, 1.f);
        gemm_mfma<false, false, true><<<g, 256, 0, stream>>>(Xb, Wk1T, bk1, B2, D_IN, (long)S_LEN * D_IN, 0, SL, L_DIM, 1.f);
        gemm_mfma<true,  false, true><<<g, 256, 0, stream>>>(Xb, Wv1T, bv1, B3, D_IN, (long)S_LEN * D_IN, 0, SL, S_LEN, 1.f);
    }
    // 2) layer-1 attention, chunked: scores -> softmax -> h = relu(attn @ v1) -> B1
    for (int c = 0; c < NB / BCH; ++c) {
        const long aoff = (long)c * BCH * SL;
        dim3 gs(S_LEN / 128, S_LEN / 128, BCH);
        gemm_mfma<false, false, false><<<gs, 256, 0, stream>>>(
            B1 + aoff, B2 + aoff, nullptr, Scb, L_DIM, SL, SL, SS, S_LEN, inv_sqrt_L);
        softmax_rows_bf16<<<dim3((unsigned)(BCH * S_LEN)), 256, 0, stream>>>(Scb);
        dim3 gp(L_DIM / 128, S_LEN / 128, BCH);
        gemm_mfma<false, true, false><<<gp, 256, 0, stream>>>(
            Scb, B3 + aoff, nullptr, B1 + aoff, S_LEN, SS, SL, SL, L_DIM, 1.f);
    }
    // 3) layer-2 Q,K from h (B1): q2->B2, k2->B3 (v2 eliminated by linearity)
    {
        dim3 g(L_DIM / 128, S_LEN / 128, NB);
        gemm_mfma<false, false, true><<<g, 256, 0, stream>>>(B1, Wq2T, bq2, B2, L_DIM, SL, 0, SL, L_DIM, 1.f);
        gemm_mfma<false, false, true><<<g, 256, 0, stream>>>(B1, Wk2T, bk2, B3, L_DIM, SL, 0, SL, L_DIM, 1.f);
    }
    // 4) layer-2 attention, chunked: scores2 -> softmax -> w = colsum(attn2)
    for (int c = 0; c < NB / BCH; ++c) {
        const long aoff = (long)c * BCH * SL;
        dim3 gs(S_LEN / 128, S_LEN / 128, BCH);
        gemm_mfma<false, false, false><<<gs, 256, 0, stream>>>(
            B2 + aoff, B3 + aoff, nullptr, Scb, L_DIM, SL, SL, SS, S_LEN, inv_sqrt_L);
        softmax_rows_bf16<<<dim3((unsigned)(BCH * S_LEN)), 256, 0, stream>>>(Scb);
        colsum_bf16<<<dim3(S_LEN / 256, BCH), 256, 0, stream>>>(Scb, w, c, BCH);
    }
    // 5) u = (w/S) @ h
    pool_u<<<dim3(NB), 256, 0, stream>>>(B1, w, u);
    // 6) phi = relu(u @ Wv2 + bv2)   (64 x 512, K=512)
    gemm_f32s<true><<<dim3(L_DIM / TILE, 1), 256, 0, stream>>>(u, Wv2, bv2, phi, NB, L_DIM, L_DIM);
    // 7) logits = phi @ We + be      (64 x 5120, K=512)
    gemm_f32s<false><<<dim3((L_DIM * K_CLS) / TILE, 1), 256, 0, stream>>>(phi, We, be, lg, NB, L_DIM * K_CLS, L_DIM);
    // 8) log_softmax over K=10
    log_softmax10<<<dim3((NB * L_DIM + 255) / 256), 256, 0, stream>>>(lg, out);
}

// Round 4
// 1226.544 us; speedup vs baseline: 5.5296x; 1.1147x over previous
//
#include <hip/hip_runtime.h>
#include <hip/hip_bf16.h>
#include <math.h>

// ---------------- problem constants ----------------
#define NB      64          // 2*N_EP batches
#define S_LEN   1024
#define IN_DIM  255
#define D_IN    256         // IN_DIM + T_DIM
#define L_DIM   512
#define K_CLS   10

#define TILE 64
#define BKK  16

typedef __hip_bfloat16 bf16;
typedef __attribute__((ext_vector_type(8))) short short8;
typedef __attribute__((ext_vector_type(4))) float f32x4;

__device__ __forceinline__ float u2f(unsigned short u) {
    return __uint_as_float(((unsigned int)u) << 16);
}
__device__ __forceinline__ unsigned short f2bu(float x) {
    bf16 b = __float2bfloat16(x);
    return *reinterpret_cast<unsigned short*>(&b);
}

// async global->LDS, 16B per lane; lds dest = wave-uniform base + lane*16
typedef const __attribute__((address_space(1))) unsigned int* gas_t;
typedef __attribute__((address_space(3))) unsigned int* las_t;
__device__ __forceinline__ void gload16(const bf16* g, bf16* l) {
    __builtin_amdgcn_global_load_lds((gas_t)(const void*)g, (las_t)(void*)l, 16, 0, 0);
}

// ---------------- build concatenated X (bf16) ----------------
__global__ __launch_bounds__(256) void build_xb(const float* __restrict__ xs,
                                                const float* __restrict__ ys,
                                                bf16* __restrict__ X) {
    long i = (long)blockIdx.x * 256 + threadIdx.x;          // over 65536*256
    long m = i >> 8;
    int  kk = (int)(i & 255);
    float v = (kk < IN_DIM) ? xs[m * IN_DIM + kk] : ys[m];
    X[i] = __float2bfloat16(v);
}

// ---------------- weight transpose fp32[K][N] -> bf16[N][K] ----------------
__global__ __launch_bounds__(256) void transpose_w(const float* __restrict__ W,
                                                   bf16* __restrict__ WT,
                                                   int K, int N) {
    int i = blockIdx.x * 256 + threadIdx.x;
    if (i >= K * N) return;
    int n = i / K, k = i - n * K;
    WT[i] = __float2bfloat16(W[(long)k * N + n]);
}

// ---------------- MFMA GEMM: C = alpha * A @ B^T (+bias) (relu) ----------------
// A: [M][K] bf16 row-major. B: [N][K] bf16 row-major. C bf16.
// TRANSC: C[col][row] with ldc (=M). EXPO: C = exp(min(alpha*acc,80)), also writes
// per-block partial row sums to ps[(bz*16 + bx*2+wn)*1024 + row]. RSCALE: scale
// output rows by rsinv[bz*1024+row] (per-batch, M must be 1024).
// 128x128 tile, 4 waves (each 64x64 = 4x4 frags of 16x16), BK=32.
// Grid is XCD-chunk-swizzled (bijective, requires nwg%8==0 else identity).
template <bool TRANSC, bool RELU, bool HASBIAS, bool EXPO, bool RSCALE>
__global__ __launch_bounds__(256) void gemm_mfma(const bf16* __restrict__ A,
                                                 const bf16* __restrict__ B,
                                                 const float* __restrict__ bias,
                                                 bf16* __restrict__ C,
                                                 int K, long sA, long sB, long sC,
                                                 int ldc, float alpha,
                                                 float* __restrict__ ps,
                                                 const float* __restrict__ rsinv) {
    __shared__ bf16 As[128 * 32];
    __shared__ bf16 Bs[128 * 32];

    // XCD-aware bijective swizzle over the whole 3D grid
    const int gx = gridDim.x, gy = gridDim.y;
    const int nwg = gx * gy * gridDim.z;
    int orig = blockIdx.x + gx * (blockIdx.y + gy * blockIdx.z);
    int id = ((nwg & 7) == 0) ? ((orig & 7) * (nwg >> 3) + (orig >> 3)) : orig;
    const int bx = id % gx;
    const int byz = id / gx;
    const int by = byz % gy;
    const int bz = byz / gy;

    A += (long)bz * sA;
    B += (long)bz * sB;
    C += (long)bz * sC;
    const int bm = by * 128;
    const int bn = bx * 128;
    const int t  = threadIdx.x;
    const int ln = t & 63;
    const int wv = t >> 6;          // wave 0..3
    const int wm = wv >> 1;         // 2x2 wave grid over 128x128
    const int wn = wv & 1;

    const bf16* gA = A + (long)(bm + (t >> 2)) * K + (t & 3) * 8;
    const bf16* gB = B + (long)(bn + (t >> 2)) * K + (t & 3) * 8;
    bf16* lA = As + wv * 512;       // wave-uniform LDS base (1024 B per wave)
    bf16* lB = Bs + wv * 512;

    f32x4 acc[4][4];
    #pragma unroll
    for (int i = 0; i < 4; ++i)
        #pragma unroll
        for (int j = 0; j < 4; ++j)
            #pragma unroll
            for (int q = 0; q < 4; ++q) acc[i][j][q] = 0.f;

    const int ro = ln & 15;
    const int ko = (ln >> 4) * 8;

    for (int k0 = 0; k0 < K; k0 += 32) {
        gload16(gA + k0,            lA);
        gload16(gA + 64 * K + k0,   lA + 2048);
        gload16(gB + k0,            lB);
        gload16(gB + 64 * K + k0,   lB + 2048);
        __syncthreads();

        short8 af[4], bg[4];
        #pragma unroll
        for (int i = 0; i < 4; ++i) {
            af[i] = *(const short8*)(As + (wm * 64 + i * 16 + ro) * 32 + ko);
            bg[i] = *(const short8*)(Bs + (wn * 64 + i * 16 + ro) * 32 + ko);
        }
        #pragma unroll
        for (int i = 0; i < 4; ++i)
            #pragma unroll
            for (int j = 0; j < 4; ++j)
                acc[i][j] = __builtin_amdgcn_mfma_f32_16x16x32_bf16(af[i], bg[j], acc[i][j], 0, 0, 0);
        __syncthreads();
    }

    // C/D layout: col = lane&15, row = (lane>>4)*4 + reg
    const int r0 = bm + wm * 64 + (ln >> 4) * 4;
    const int c0 = bn + wn * 64 + (ln & 15);

    if constexpr (TRANSC) {
        #pragma unroll
        for (int i = 0; i < 4; ++i) {
            const int rowb = r0 + i * 16;
            #pragma unroll
            for (int j = 0; j < 4; ++j) {
                const int col = c0 + j * 16;
                const float bi = HASBIAS ? bias[col] : 0.f;
                ushort4 o;
                float v0 = acc[i][j][0] * alpha + bi;
                float v1 = acc[i][j][1] * alpha + bi;
                float v2 = acc[i][j][2] * alpha + bi;
                float v3 = acc[i][j][3] * alpha + bi;
                if (RELU) { v0 = fmaxf(v0, 0.f); v1 = fmaxf(v1, 0.f); v2 = fmaxf(v2, 0.f); v3 = fmaxf(v3, 0.f); }
                o.x = f2bu(v0); o.y = f2bu(v1); o.z = f2bu(v2); o.w = f2bu(v3);
                *(ushort4*)(C + (long)col * ldc + rowb) = o;
            }
        }
    } else if constexpr (EXPO) {
        float sloc[4][4];
        #pragma unroll
        for (int i = 0; i < 4; ++i)
            #pragma unroll
            for (int q = 0; q < 4; ++q) sloc[i][q] = 0.f;
        #pragma unroll
        for (int i = 0; i < 4; ++i) {
            #pragma unroll
            for (int j = 0; j < 4; ++j) {
                const int col = c0 + j * 16;
                #pragma unroll
                for (int q = 0; q < 4; ++q) {
                    float e = __expf(fminf(acc[i][j][q] * alpha, 80.f));
                    sloc[i][q] += e;
                    C[(long)(r0 + i * 16 + q) * ldc + col] = __float2bfloat16(e);
                }
            }
        }
        // reduce partial row sums across the 16 lanes holding one row's columns
        #pragma unroll
        for (int o = 1; o < 16; o <<= 1)
            #pragma unroll
            for (int i = 0; i < 4; ++i)
                #pragma unroll
                for (int q = 0; q < 4; ++q)
                    sloc[i][q] += __shfl_xor(sloc[i][q], o, 64);
        if ((ln & 15) == 0) {
            const int cb = bx * 2 + wn;
            const int rb = bm + wm * 64 + (ln >> 4) * 4;
            #pragma unroll
            for (int i = 0; i < 4; ++i)
                #pragma unroll
                for (int q = 0; q < 4; ++q)
                    ps[((long)bz * 16 + cb) * 1024 + rb + i * 16 + q] = sloc[i][q];
        }
    } else {
        float rsv[4][4];
        if constexpr (RSCALE) {
            const int rb = bm + wm * 64 + (ln >> 4) * 4;
            #pragma unroll
            for (int i = 0; i < 4; ++i)
                #pragma unroll
                for (int q = 0; q < 4; ++q)
                    rsv[i][q] = rsinv[(long)bz * 1024 + rb + i * 16 + q];
        }
        #pragma unroll
        for (int i = 0; i < 4; ++i) {
            #pragma unroll
            for (int j = 0; j < 4; ++j) {
                const int col = c0 + j * 16;
                const float bi = HASBIAS ? bias[col] : 0.f;
                #pragma unroll
                for (int q = 0; q < 4; ++q) {
                    float v = acc[i][j][q] * alpha + bi;
                    if (RSCALE) v *= rsv[i][q];
                    if (RELU) v = fmaxf(v, 0.f);
                    C[(long)(r0 + i * 16 + q) * ldc + col] = __float2bfloat16(v);
                }
            }
        }
    }
}

// ---------------- rsinv = 1 / sum of 16 partial row sums ----------------
__global__ __launch_bounds__(256) void rowsum_inv(const float* __restrict__ ps,
                                                  float* __restrict__ rsinv, int n) {
    int i = blockIdx.x * 256 + threadIdx.x;
    if (i >= n) return;
    const int b = i >> 10, row = i & 1023;
    float s = 0.f;
    #pragma unroll
    for (int cb = 0; cb < 16; ++cb) s += ps[((long)b * 16 + cb) * 1024 + row];
    rsinv[i] = 1.f / s;
}

// ---------------- tiny fp32 tiled GEMM (tail, M=64) ----------------
template <bool RELU>
__global__ __launch_bounds__(256) void gemm_f32s(const float* __restrict__ A,
                                                 const float* __restrict__ B,
                                                 const float* __restrict__ bias,
                                                 float* __restrict__ C,
                                                 int M, int N, int K) {
    __shared__ float As[BKK][TILE + 1];
    __shared__ float Bs[BKK][TILE + 1];
    const int bm = blockIdx.y * TILE;
    const int bn = blockIdx.x * TILE;
    const int t  = threadIdx.x;
    const int tx = t & 15, ty = t >> 4;
    float acc[4][4] = {};
    for (int k0 = 0; k0 < K; k0 += BKK) {
        {
            int m  = t >> 2;
            int kq = (t & 3) * 4;
            const float4 av = *(const float4*)(A + (long)(bm + m) * K + k0 + kq);
            As[kq + 0][m] = av.x; As[kq + 1][m] = av.y;
            As[kq + 2][m] = av.z; As[kq + 3][m] = av.w;
        }
        {
            int k  = t >> 4;
            int nq = (t & 15) * 4;
            const float4 bv = *(const float4*)(B + (long)(k0 + k) * N + bn + nq);
            Bs[k][nq + 0] = bv.x; Bs[k][nq + 1] = bv.y;
            Bs[k][nq + 2] = bv.z; Bs[k][nq + 3] = bv.w;
        }
        __syncthreads();
        #pragma unroll
        for (int k = 0; k < BKK; ++k) {
            float a[4], bb[4];
            #pragma unroll
            for (int i = 0; i < 4; ++i) a[i] = As[k][ty * 4 + i];
            #pragma unroll
            for (int j = 0; j < 4; ++j) bb[j] = Bs[k][tx * 4 + j];
            #pragma unroll
            for (int i = 0; i < 4; ++i)
                #pragma unroll
                for (int j = 0; j < 4; ++j)
                    acc[i][j] = fmaf(a[i], bb[j], acc[i][j]);
        }
        __syncthreads();
    }
    #pragma unroll
    for (int i = 0; i < 4; ++i) {
        const int row  = bm + ty * 4 + i;
        const int col0 = bn + tx * 4;
        #pragma unroll
        for (int j = 0; j < 4; ++j) {
            float x = acc[i][j] + bias[col0 + j];
            if (RELU) x = fmaxf(x, 0.f);
            C[(long)row * N + col0 + j] = x;
        }
    }
}

// ---------------- scaled column sums of P-tilde chunk ----------------
// w[col] = sum_q Ptilde[q][col] * rsinv[q]
__global__ __launch_bounds__(256) void colsum_scaled(const bf16* __restrict__ Sc,
                                                     const float* __restrict__ rsinv,
                                                     float* __restrict__ w,
                                                     int c0, int bch) {
    const int b = blockIdx.y;                          // 0..bch-1
    const int c = blockIdx.x * 256 + threadIdx.x;      // grid.x = 4
    __shared__ float ri[S_LEN];
    for (int i = threadIdx.x; i < S_LEN; i += 256) ri[i] = rsinv[(long)b * S_LEN + i];
    __syncthreads();
    const bf16* p = Sc + (long)b * (S_LEN * S_LEN) + c;
    float acc = 0.f;
    for (int q = 0; q < S_LEN; ++q) acc += __bfloat162float(p[(long)q * S_LEN]) * ri[q];
    w[(c0 * bch + b) * S_LEN + c] = acc;
}

// ---------------- u = (w/S) @ h  (per batch) ----------------
__global__ __launch_bounds__(256) void pool_u(const bf16* __restrict__ h,
                                              const float* __restrict__ w,
                                              float* __restrict__ u) {
    const int b = blockIdx.x;           // 64 batches
    const int t = threadIdx.x;          // owns d = 2t, 2t+1
    __shared__ float wl[S_LEN];
    for (int i = t; i < S_LEN; i += 256) wl[i] = w[b * S_LEN + i];
    __syncthreads();
    const bf16* hp = h + (long)b * S_LEN * L_DIM;
    float a0 = 0.f, a1 = 0.f;
    for (int q = 0; q < S_LEN; ++q) {
        ushort2 uv = *(const ushort2*)(hp + (long)q * L_DIM + t * 2);
        float ww = wl[q];
        a0 = fmaf(ww, u2f(uv.x), a0);
        a1 = fmaf(ww, u2f(uv.y), a1);
    }
    u[b * L_DIM + t * 2 + 0] = a0 * (1.f / (float)S_LEN);
    u[b * L_DIM + t * 2 + 1] = a1 * (1.f / (float)S_LEN);
}

// ---------------- log_softmax over groups of 10 ----------------
__global__ __launch_bounds__(256) void log_softmax10(const float* __restrict__ logits,
                                                     float* __restrict__ out) {
    const int t = blockIdx.x * 256 + threadIdx.x;     // 64*512 groups
    if (t >= NB * L_DIM) return;
    const float* p = logits + (long)t * K_CLS;
    float v[K_CLS], m = -INFINITY;
    #pragma unroll
    for (int k = 0; k < K_CLS; ++k) { v[k] = p[k]; m = fmaxf(m, v[k]); }
    float s = 0.f;
    #pragma unroll
    for (int k = 0; k < K_CLS; ++k) s += __expf(v[k] - m);
    const float lse = m + logf(s);
    float* o = out + (long)t * K_CLS;
    #pragma unroll
    for (int k = 0; k < K_CLS; ++k) o[k] = v[k] - lse;
}

// ---------------- host launch ----------------
extern "C" void kernel_launch(void* const* d_in, const int* in_sizes, int n_in,
                              void* d_out, int out_size, void* d_ws, size_t ws_size,
                              hipStream_t stream) {
    const float* xs  = (const float*)d_in[0];
    const float* ys  = (const float*)d_in[1];
    const float* Wq1 = (const float*)d_in[2];  const float* bq1 = (const float*)d_in[3];
    const float* Wk1 = (const float*)d_in[4];  const float* bk1 = (const float*)d_in[5];
    const float* Wv1 = (const float*)d_in[6];  const float* bv1 = (const float*)d_in[7];
    const float* Wq2 = (const float*)d_in[8];  const float* bq2 = (const float*)d_in[9];
    const float* Wk2 = (const float*)d_in[10]; const float* bk2 = (const float*)d_in[11];
    const float* Wv2 = (const float*)d_in[12]; const float* bv2 = (const float*)d_in[13];
    const float* We  = (const float*)d_in[14]; const float* be  = (const float*)d_in[15];
    float* out = (float*)d_out;

    const long M  = (long)NB * S_LEN;        // 65536
    const long QL = M * L_DIM;               // 33.5M elems
    const long SL = (long)S_LEN * L_DIM;     // per-batch activation stride (also V1T stride)
    const long SS = (long)S_LEN * S_LEN;     // per-batch score stride

    // ---- workspace layout (bf16 first, then fp32) ----
    bf16* Xb  = (bf16*)d_ws;                 // 33.5 MB
    bf16* B1  = Xb + M * D_IN;               // 67.1 MB  (q1 -> h)
    bf16* B2  = B1 + QL;                     // 67.1 MB  (k1 -> q2)
    bf16* B3  = B2 + QL;                     // 67.1 MB  (v1T -> k2)
    bf16* WTb = B3 + QL;                     // 1.8 MB: Wq1T,Wk1T,Wv1T (512x256), Wq2T,Wk2T (512x512)
    bf16* Wq1T = WTb;
    bf16* Wk1T = Wq1T + L_DIM * D_IN;
    bf16* Wv1T = Wk1T + L_DIM * D_IN;
    bf16* Wq2T = Wv1T + L_DIM * D_IN;
    bf16* Wk2T = Wq2T + L_DIM * L_DIM;
    bf16* Scb  = Wk2T + L_DIM * L_DIM;       // BCH * 2 MB score chunk

    // adaptive chunk size by ws_size
    const size_t base_b = (size_t)((char*)Scb - (char*)d_ws);
    const size_t f32_b  = (size_t)(M + 2 * NB * L_DIM + NB * L_DIM * K_CLS
                                   + 32 * 16 * 1024 + 32 * 1024) * 4 + 256;
    int BCH = 32;
    while (BCH > 8 && base_b + (size_t)BCH * SS * 2 + f32_b > ws_size) BCH >>= 1;

    float* w     = (float*)(Scb + (long)BCH * SS);
    float* u     = w   + M;
    float* phi   = u   + NB * L_DIM;
    float* lg    = phi + NB * L_DIM;
    float* ps    = lg  + NB * L_DIM * K_CLS;     // 16 partial row sums x 32 batches
    float* rsinv = ps  + 32 * 16 * 1024;         // 1/rowsum, 32 batches

    const float inv_sqrt_L = 0.044194173824159216f;  // 1/sqrt(512)

    // 0) X = concat(x_sets, y_sets) -> bf16 ; transpose weights -> bf16
    build_xb<<<dim3((unsigned)(M * D_IN / 256)), 256, 0, stream>>>(xs, ys, Xb);
    transpose_w<<<dim3(512), 256, 0, stream>>>(Wq1, Wq1T, D_IN, L_DIM);
    transpose_w<<<dim3(512), 256, 0, stream>>>(Wk1, Wk1T, D_IN, L_DIM);
    transpose_w<<<dim3(512), 256, 0, stream>>>(Wv1, Wv1T, D_IN, L_DIM);
    transpose_w<<<dim3(1024), 256, 0, stream>>>(Wq2, Wq2T, L_DIM, L_DIM);
    transpose_w<<<dim3(1024), 256, 0, stream>>>(Wk2, Wk2T, L_DIM, L_DIM);

    // 1) layer-1 QKV: q1->B1, k1->B2 (normal), v1->B3 TRANSPOSED per batch [512][1024]
    {
        dim3 g(L_DIM / 128, S_LEN / 128, NB);
        gemm_mfma<false, false, true, false, false><<<g, 256, 0, stream>>>(Xb, Wq1T, bq1, B1, D_IN, (long)S_LEN * D_IN, 0, SL, L_DIM, 1.f, nullptr, nullptr);
        gemm_mfma<false, false, true, false, false><<<g, 256, 0, stream>>>(Xb, Wk1T, bk1, B2, D_IN, (long)S_LEN * D_IN, 0, SL, L_DIM, 1.f, nullptr, nullptr);
        gemm_mfma<true,  false, true, false, false><<<g, 256, 0, stream>>>(Xb, Wv1T, bv1, B3, D_IN, (long)S_LEN * D_IN, 0, SL, S_LEN, 1.f, nullptr, nullptr);
    }
    // 2) layer-1 attention, chunked: Ptilde=exp(scores) -> rowsum -> h = relu((P@v)/l) -> B1
    for (int c = 0; c < NB / BCH; ++c) {
        const long aoff = (long)c * BCH * SL;
        dim3 gs(S_LEN / 128, S_LEN / 128, BCH);
        gemm_mfma<false, false, false, true, false><<<gs, 256, 0, stream>>>(
            B1 + aoff, B2 + aoff, nullptr, Scb, L_DIM, SL, SL, SS, S_LEN, inv_sqrt_L, ps, nullptr);
        rowsum_inv<<<dim3((unsigned)(BCH * S_LEN / 256)), 256, 0, stream>>>(ps, rsinv, BCH * S_LEN);
        dim3 gp(L_DIM / 128, S_LEN / 128, BCH);
        gemm_mfma<false, true, false, false, true><<<gp, 256, 0, stream>>>(
            Scb, B3 + aoff, nullptr, B1 + aoff, S_LEN, SS, SL, SL, L_DIM, 1.f, nullptr, rsinv);
    }
    // 3) layer-2 Q,K from h (B1): q2->B2, k2->B3 (v2 eliminated by linearity)
    {
        dim3 g(L_DIM / 128, S_LEN / 128, NB);
        gemm_mfma<false, false, true, false, false><<<g, 256, 0, stream>>>(B1, Wq2T, bq2, B2, L_DIM, SL, 0, SL, L_DIM, 1.f, nullptr, nullptr);
        gemm_mfma<false, false, true, false, false><<<g, 256, 0, stream>>>(B1, Wk2T, bk2, B3, L_DIM, SL, 0, SL, L_DIM, 1.f, nullptr, nullptr);
    }
    // 4) layer-2 attention, chunked: Ptilde -> rowsum -> w = colsum(P * rsinv)
    for (int c = 0; c < NB / BCH; ++c) {
        const long aoff = (long)c * BCH * SL;
        dim3 gs(S_LEN / 128, S_LEN / 128, BCH);
        gemm_mfma<false, false, false, true, false><<<gs, 256, 0, stream>>>(
            B2 + aoff, B3 + aoff, nullptr, Scb, L_DIM, SL, SL, SS, S_LEN, inv_sqrt_L, ps, nullptr);
        rowsum_inv<<<dim3((unsigned)(BCH * S_LEN / 256)), 256, 0, stream>>>(ps, rsinv, BCH * S_LEN);
        colsum_scaled<<<dim3(S_LEN / 256, BCH), 256, 0, stream>>>(Scb, rsinv, w, c, BCH);
    }
    // 5) u = (w/S) @ h
    pool_u<<<dim3(NB), 256, 0, stream>>>(B1, w, u);
    // 6) phi = relu(u @ Wv2 + bv2)   (64 x 512, K=512)
    gemm_f32s<true><<<dim3(L_DIM / TILE, 1), 256, 0, stream>>>(u, Wv2, bv2, phi, NB, L_DIM, L_DIM);
    // 7) logits = phi @ We + be      (64 x 5120, K=512)
    gemm_f32s<false><<<dim3((L_DIM * K_CLS) / TILE, 1), 256, 0, stream>>>(phi, We, be, lg, NB, L_DIM * K_CLS, L_DIM);
    // 8) log_softmax over K=10
    log_softmax10<<<dim3((NB * L_DIM + 255) / 256), 256, 0, stream>>>(lg, out);
}

// Round 5
// 1072.176 us; speedup vs baseline: 6.3257x; 1.1440x over previous
//
#include <hip/hip_runtime.h>
#include <hip/hip_bf16.h>
#include <math.h>

// ---------------- problem constants ----------------
#define NB      64          // 2*N_EP batches
#define S_LEN   1024
#define IN_DIM  255
#define D_IN    256         // IN_DIM + T_DIM
#define L_DIM   512
#define K_CLS   10

#define TILE 64
#define BKK  16

typedef __hip_bfloat16 bf16;
typedef __attribute__((ext_vector_type(8))) short short8;
typedef __attribute__((ext_vector_type(4))) float f32x4;

__device__ __forceinline__ float u2f(unsigned short u) {
    return __uint_as_float(((unsigned int)u) << 16);
}
__device__ __forceinline__ unsigned short f2bu(float x) {
    bf16 b = __float2bfloat16(x);
    return *reinterpret_cast<unsigned short*>(&b);
}

// async global->LDS, 16B per lane; lds dest = wave-uniform base + lane*16
typedef const __attribute__((address_space(1))) unsigned int* gas_t;
typedef __attribute__((address_space(3))) unsigned int* las_t;
__device__ __forceinline__ void gload16(const bf16* g, bf16* l) {
    __builtin_amdgcn_global_load_lds((gas_t)(const void*)g, (las_t)(void*)l, 16, 0, 0);
}

// ---------------- build concatenated X (bf16) ----------------
__global__ __launch_bounds__(256) void build_xb(const float* __restrict__ xs,
                                                const float* __restrict__ ys,
                                                bf16* __restrict__ X) {
    long i = (long)blockIdx.x * 256 + threadIdx.x;          // over 65536*256
    long m = i >> 8;
    int  kk = (int)(i & 255);
    float v = (kk < IN_DIM) ? xs[m * IN_DIM + kk] : ys[m];
    X[i] = __float2bfloat16(v);
}

// ---------------- all 5 weight transposes in one dispatch ----------------
// src: fp32 [K][512] -> dst: bf16 [512][K].  Segments: 3x(K=256), 2x(K=512).
struct TW {
    const float* s0; const float* s1; const float* s2; const float* s3; const float* s4;
    bf16* d0; bf16* d1; bf16* d2; bf16* d3; bf16* d4;
};
__global__ __launch_bounds__(256) void transpose_all(TW tw) {
    int i = blockIdx.x * 256 + threadIdx.x;    // 0 .. 917504
    const float* S; bf16* D; int K, j;
    if (i < 131072)      { S = tw.s0; D = tw.d0; K = 256; j = i; }
    else if (i < 262144) { S = tw.s1; D = tw.d1; K = 256; j = i - 131072; }
    else if (i < 393216) { S = tw.s2; D = tw.d2; K = 256; j = i - 262144; }
    else if (i < 655360) { S = tw.s3; D = tw.d3; K = 512; j = i - 393216; }
    else                 { S = tw.s4; D = tw.d4; K = 512; j = i - 655360; }
    int n = j / K, k = j - n * K;
    D[j] = __float2bfloat16(S[(long)k * 512 + n]);
}

// ---------------- MFMA GEMM: C = alpha * A @ B^T (+bias) (relu) ----------------
// A: [M][K] bf16 row-major. B: [N][K] bf16 row-major. C bf16.
// TRANSC: C[col][row] with ldc (=M). EXPO: C = exp(min(alpha*acc,80)), also writes
// per-block partial row sums to ps[(bz*16 + bx*2+wn)*1024 + row]. RSCALE: scale
// output rows by rsinv[bz*1024+row] (per-batch, M must be 1024).
// 128x128 tile, 4 waves (each 64x64 = 4x4 frags of 16x16), BK=32,
// 2-phase double-buffered LDS: stage(t+1) issued before compute(t), one barrier/K-step.
// Grid is XCD-chunk-swizzled (bijective, requires nwg%8==0 else identity).
template <bool TRANSC, bool RELU, bool HASBIAS, bool EXPO, bool RSCALE>
__global__ __launch_bounds__(256) void gemm_mfma(const bf16* __restrict__ A,
                                                 const bf16* __restrict__ B,
                                                 const float* __restrict__ bias,
                                                 bf16* __restrict__ C,
                                                 int K, long sA, long sB, long sC,
                                                 int ldc, float alpha,
                                                 float* __restrict__ ps,
                                                 const float* __restrict__ rsinv) {
    __shared__ bf16 As[2][128 * 32];
    __shared__ bf16 Bs[2][128 * 32];

    // XCD-aware bijective swizzle over the whole 3D grid
    const int gx = gridDim.x, gy = gridDim.y;
    const int nwg = gx * gy * gridDim.z;
    int orig = blockIdx.x + gx * (blockIdx.y + gy * blockIdx.z);
    int id = ((nwg & 7) == 0) ? ((orig & 7) * (nwg >> 3) + (orig >> 3)) : orig;
    const int bx = id % gx;
    const int byz = id / gx;
    const int by = byz % gy;
    const int bz = byz / gy;

    A += (long)bz * sA;
    B += (long)bz * sB;
    C += (long)bz * sC;
    const int bm = by * 128;
    const int bn = bx * 128;
    const int t  = threadIdx.x;
    const int ln = t & 63;
    const int wv = t >> 6;          // wave 0..3
    const int wm = wv >> 1;         // 2x2 wave grid over 128x128
    const int wn = wv & 1;

    const bf16* gA = A + (long)(bm + (t >> 2)) * K + (t & 3) * 8;
    const bf16* gB = B + (long)(bn + (t >> 2)) * K + (t & 3) * 8;
    const int wb = wv * 512;        // wave-uniform LDS base (1024 B per wave)

    f32x4 acc[4][4];
    #pragma unroll
    for (int i = 0; i < 4; ++i)
        #pragma unroll
        for (int j = 0; j < 4; ++j)
            #pragma unroll
            for (int q = 0; q < 4; ++q) acc[i][j][q] = 0.f;

    const int ro = ln & 15;
    const int ko = (ln >> 4) * 8;

    auto stage = [&](int buf, int k0) {
        gload16(gA + k0,          As[buf] + wb);
        gload16(gA + 64 * K + k0, As[buf] + wb + 2048);
        gload16(gB + k0,          Bs[buf] + wb);
        gload16(gB + 64 * K + k0, Bs[buf] + wb + 2048);
    };

    const int nt = K >> 5;
    stage(0, 0);
    __syncthreads();

    for (int tt = 0; tt < nt; ++tt) {
        const int cur = tt & 1;
        if (tt + 1 < nt) stage(cur ^ 1, (tt + 1) << 5);   // prefetch under compute

        short8 af[4], bg[4];
        #pragma unroll
        for (int i = 0; i < 4; ++i) {
            af[i] = *(const short8*)(As[cur] + (wm * 64 + i * 16 + ro) * 32 + ko);
            bg[i] = *(const short8*)(Bs[cur] + (wn * 64 + i * 16 + ro) * 32 + ko);
        }
        #pragma unroll
        for (int i = 0; i < 4; ++i)
            #pragma unroll
            for (int j = 0; j < 4; ++j)
                acc[i][j] = __builtin_amdgcn_mfma_f32_16x16x32_bf16(af[i], bg[j], acc[i][j], 0, 0, 0);
        __syncthreads();   // drains prefetch vmcnt + orders buffer reuse
    }

    // C/D layout: col = lane&15, row = (lane>>4)*4 + reg
    const int r0 = bm + wm * 64 + (ln >> 4) * 4;
    const int c0 = bn + wn * 64 + (ln & 15);

    if constexpr (TRANSC) {
        #pragma unroll
        for (int i = 0; i < 4; ++i) {
            const int rowb = r0 + i * 16;
            #pragma unroll
            for (int j = 0; j < 4; ++j) {
                const int col = c0 + j * 16;
                const float bi = HASBIAS ? bias[col] : 0.f;
                ushort4 o;
                float v0 = acc[i][j][0] * alpha + bi;
                float v1 = acc[i][j][1] * alpha + bi;
                float v2 = acc[i][j][2] * alpha + bi;
                float v3 = acc[i][j][3] * alpha + bi;
                if (RELU) { v0 = fmaxf(v0, 0.f); v1 = fmaxf(v1, 0.f); v2 = fmaxf(v2, 0.f); v3 = fmaxf(v3, 0.f); }
                o.x = f2bu(v0); o.y = f2bu(v1); o.z = f2bu(v2); o.w = f2bu(v3);
                *(ushort4*)(C + (long)col * ldc + rowb) = o;
            }
        }
    } else if constexpr (EXPO) {
        float sloc[4][4];
        #pragma unroll
        for (int i = 0; i < 4; ++i)
            #pragma unroll
            for (int q = 0; q < 4; ++q) sloc[i][q] = 0.f;
        #pragma unroll
        for (int i = 0; i < 4; ++i) {
            #pragma unroll
            for (int j = 0; j < 4; ++j) {
                const int col = c0 + j * 16;
                #pragma unroll
                for (int q = 0; q < 4; ++q) {
                    float e = __expf(fminf(acc[i][j][q] * alpha, 80.f));
                    sloc[i][q] += e;
                    C[(long)(r0 + i * 16 + q) * ldc + col] = __float2bfloat16(e);
                }
            }
        }
        // reduce partial row sums across the 16 lanes holding one row's columns
        #pragma unroll
        for (int o = 1; o < 16; o <<= 1)
            #pragma unroll
            for (int i = 0; i < 4; ++i)
                #pragma unroll
                for (int q = 0; q < 4; ++q)
                    sloc[i][q] += __shfl_xor(sloc[i][q], o, 64);
        if ((ln & 15) == 0) {
            const int cb = bx * 2 + wn;
            const int rb = bm + wm * 64 + (ln >> 4) * 4;
            #pragma unroll
            for (int i = 0; i < 4; ++i)
                #pragma unroll
                for (int q = 0; q < 4; ++q)
                    ps[((long)bz * 16 + cb) * 1024 + rb + i * 16 + q] = sloc[i][q];
        }
    } else {
        float rsv[4][4];
        if constexpr (RSCALE) {
            const int rb = bm + wm * 64 + (ln >> 4) * 4;
            #pragma unroll
            for (int i = 0; i < 4; ++i)
                #pragma unroll
                for (int q = 0; q < 4; ++q)
                    rsv[i][q] = rsinv[(long)bz * 1024 + rb + i * 16 + q];
        }
        #pragma unroll
        for (int i = 0; i < 4; ++i) {
            #pragma unroll
            for (int j = 0; j < 4; ++j) {
                const int col = c0 + j * 16;
                const float bi = HASBIAS ? bias[col] : 0.f;
                #pragma unroll
                for (int q = 0; q < 4; ++q) {
                    float v = acc[i][j][q] * alpha + bi;
                    if (RSCALE) v *= rsv[i][q];
                    if (RELU) v = fmaxf(v, 0.f);
                    C[(long)(r0 + i * 16 + q) * ldc + col] = __float2bfloat16(v);
                }
            }
        }
    }
}

// ---------------- rsinv = 1 / sum of 16 partial row sums ----------------
__global__ __launch_bounds__(256) void rowsum_inv(const float* __restrict__ ps,
                                                  float* __restrict__ rsinv, int n) {
    int i = blockIdx.x * 256 + threadIdx.x;
    if (i >= n) return;
    const int b = i >> 10, row = i & 1023;
    float s = 0.f;
    #pragma unroll
    for (int cb = 0; cb < 16; ++cb) s += ps[((long)b * 16 + cb) * 1024 + row];
    rsinv[i] = 1.f / s;
}

// ---------------- tiny fp32 tiled GEMM (tail, M=64) ----------------
template <bool RELU>
__global__ __launch_bounds__(256) void gemm_f32s(const float* __restrict__ A,
                                                 const float* __restrict__ B,
                                                 const float* __restrict__ bias,
                                                 float* __restrict__ C,
                                                 int M, int N, int K) {
    __shared__ float As[BKK][TILE + 1];
    __shared__ float Bs[BKK][TILE + 1];
    const int bm = blockIdx.y * TILE;
    const int bn = blockIdx.x * TILE;
    const int t  = threadIdx.x;
    const int tx = t & 15, ty = t >> 4;
    float acc[4][4] = {};
    for (int k0 = 0; k0 < K; k0 += BKK) {
        {
            int m  = t >> 2;
            int kq = (t & 3) * 4;
            const float4 av = *(const float4*)(A + (long)(bm + m) * K + k0 + kq);
            As[kq + 0][m] = av.x; As[kq + 1][m] = av.y;
            As[kq + 2][m] = av.z; As[kq + 3][m] = av.w;
        }
        {
            int k  = t >> 4;
            int nq = (t & 15) * 4;
            const float4 bv = *(const float4*)(B + (long)(k0 + k) * N + bn + nq);
            Bs[k][nq + 0] = bv.x; Bs[k][nq + 1] = bv.y;
            Bs[k][nq + 2] = bv.z; Bs[k][nq + 3] = bv.w;
        }
        __syncthreads();
        #pragma unroll
        for (int k = 0; k < BKK; ++k) {
            float a[4], bb[4];
            #pragma unroll
            for (int i = 0; i < 4; ++i) a[i] = As[k][ty * 4 + i];
            #pragma unroll
            for (int j = 0; j < 4; ++j) bb[j] = Bs[k][tx * 4 + j];
            #pragma unroll
            for (int i = 0; i < 4; ++i)
                #pragma unroll
                for (int j = 0; j < 4; ++j)
                    acc[i][j] = fmaf(a[i], bb[j], acc[i][j]);
        }
        __syncthreads();
    }
    #pragma unroll
    for (int i = 0; i < 4; ++i) {
        const int row  = bm + ty * 4 + i;
        const int col0 = bn + tx * 4;
        #pragma unroll
        for (int j = 0; j < 4; ++j) {
            float x = acc[i][j] + bias[col0 + j];
            if (RELU) x = fmaxf(x, 0.f);
            C[(long)row * N + col0 + j] = x;
        }
    }
}

// ---------------- scaled column sums of P-tilde chunk ----------------
// w[col] = sum_q Ptilde[q][col] * rsinv[q]
__global__ __launch_bounds__(256) void colsum_scaled(const bf16* __restrict__ Sc,
                                                     const float* __restrict__ rsinv,
                                                     float* __restrict__ w,
                                                     int c0, int bch) {
    const int b = blockIdx.y;                          // 0..bch-1
    const int c = blockIdx.x * 256 + threadIdx.x;      // grid.x = 4
    __shared__ float ri[S_LEN];
    for (int i = threadIdx.x; i < S_LEN; i += 256) ri[i] = rsinv[(long)b * S_LEN + i];
    __syncthreads();
    const bf16* p = Sc + (long)b * (S_LEN * S_LEN) + c;
    float acc = 0.f;
    for (int q = 0; q < S_LEN; ++q) acc += __bfloat162float(p[(long)q * S_LEN]) * ri[q];
    w[(c0 * bch + b) * S_LEN + c] = acc;
}

// ---------------- u partials: up[b][qq][d] = sum_{q in qq-chunk} w[q] h[q][d] ----------------
__global__ __launch_bounds__(256) void pool_u_part(const bf16* __restrict__ h,
                                                   const float* __restrict__ w,
                                                   float* __restrict__ up) {
    const int b  = blockIdx.x;          // 64 batches
    const int qq = blockIdx.y;          // 4 q-chunks of 256
    const int t  = threadIdx.x;         // owns d = 2t, 2t+1
    __shared__ float wl[256];
    wl[t] = w[b * S_LEN + qq * 256 + t];
    __syncthreads();
    const bf16* hp = h + (long)b * S_LEN * L_DIM + (long)qq * 256 * L_DIM;
    float a0 = 0.f, a1 = 0.f;
    for (int q = 0; q < 256; ++q) {
        ushort2 uv = *(const ushort2*)(hp + (long)q * L_DIM + t * 2);
        float ww = wl[q];
        a0 = fmaf(ww, u2f(uv.x), a0);
        a1 = fmaf(ww, u2f(uv.y), a1);
    }
    up[((long)(b * 4 + qq)) * L_DIM + t * 2 + 0] = a0;
    up[((long)(b * 4 + qq)) * L_DIM + t * 2 + 1] = a1;
}

__global__ __launch_bounds__(256) void pool_u_red(const float* __restrict__ up,
                                                  float* __restrict__ u) {
    int i = blockIdx.x * 256 + threadIdx.x;   // 64*512
    if (i >= NB * L_DIM) return;
    int b = i >> 9, d = i & 511;
    float s = up[((long)(b * 4 + 0)) * L_DIM + d] + up[((long)(b * 4 + 1)) * L_DIM + d]
            + up[((long)(b * 4 + 2)) * L_DIM + d] + up[((long)(b * 4 + 3)) * L_DIM + d];
    u[i] = s * (1.f / (float)S_LEN);
}

// ---------------- log_softmax over groups of 10 ----------------
__global__ __launch_bounds__(256) void log_softmax10(const float* __restrict__ logits,
                                                     float* __restrict__ out) {
    const int t = blockIdx.x * 256 + threadIdx.x;     // 64*512 groups
    if (t >= NB * L_DIM) return;
    const float* p = logits + (long)t * K_CLS;
    float v[K_CLS], m = -INFINITY;
    #pragma unroll
    for (int k = 0; k < K_CLS; ++k) { v[k] = p[k]; m = fmaxf(m, v[k]); }
    float s = 0.f;
    #pragma unroll
    for (int k = 0; k < K_CLS; ++k) s += __expf(v[k] - m);
    const float lse = m + logf(s);
    float* o = out + (long)t * K_CLS;
    #pragma unroll
    for (int k = 0; k < K_CLS; ++k) o[k] = v[k] - lse;
}

// ---------------- host launch ----------------
extern "C" void kernel_launch(void* const* d_in, const int* in_sizes, int n_in,
                              void* d_out, int out_size, void* d_ws, size_t ws_size,
                              hipStream_t stream) {
    const float* xs  = (const float*)d_in[0];
    const float* ys  = (const float*)d_in[1];
    const float* Wq1 = (const float*)d_in[2];  const float* bq1 = (const float*)d_in[3];
    const float* Wk1 = (const float*)d_in[4];  const float* bk1 = (const float*)d_in[5];
    const float* Wv1 = (const float*)d_in[6];  const float* bv1 = (const float*)d_in[7];
    const float* Wq2 = (const float*)d_in[8];  const float* bq2 = (const float*)d_in[9];
    const float* Wk2 = (const float*)d_in[10]; const float* bk2 = (const float*)d_in[11];
    const float* Wv2 = (const float*)d_in[12]; const float* bv2 = (const float*)d_in[13];
    const float* We  = (const float*)d_in[14]; const float* be  = (const float*)d_in[15];
    float* out = (float*)d_out;

    const long M  = (long)NB * S_LEN;        // 65536
    const long QL = M * L_DIM;               // 33.5M elems
    const long SL = (long)S_LEN * L_DIM;     // per-batch activation stride (also V1T stride)
    const long SS = (long)S_LEN * S_LEN;     // per-batch score stride

    // ---- workspace layout (bf16 first, then fp32) ----
    bf16* Xb  = (bf16*)d_ws;                 // 33.5 MB
    bf16* B1  = Xb + M * D_IN;               // 67.1 MB  (q1 -> h)
    bf16* B2  = B1 + QL;                     // 67.1 MB  (k1 -> q2)
    bf16* B3  = B2 + QL;                     // 67.1 MB  (v1T -> k2)
    bf16* WTb = B3 + QL;                     // 1.8 MB: Wq1T,Wk1T,Wv1T (512x256), Wq2T,Wk2T (512x512)
    bf16* Wq1T = WTb;
    bf16* Wk1T = Wq1T + L_DIM * D_IN;
    bf16* Wv1T = Wk1T + L_DIM * D_IN;
    bf16* Wq2T = Wv1T + L_DIM * D_IN;
    bf16* Wk2T = Wq2T + L_DIM * L_DIM;
    bf16* Scb  = Wk2T + L_DIM * L_DIM;       // BCH * 2 MB score chunk

    // adaptive chunk size by ws_size
    const size_t base_b = (size_t)((char*)Scb - (char*)d_ws);
    const size_t f32_b  = (size_t)(M + 2 * NB * L_DIM + NB * L_DIM * K_CLS
                                   + 32 * 16 * 1024 + 32 * 1024 + 4 * NB * L_DIM) * 4 + 256;
    int BCH = 32;
    while (BCH > 8 && base_b + (size_t)BCH * SS * 2 + f32_b > ws_size) BCH >>= 1;

    float* w     = (float*)(Scb + (long)BCH * SS);
    float* u     = w   + M;
    float* phi   = u   + NB * L_DIM;
    float* lg    = phi + NB * L_DIM;
    float* ps    = lg  + NB * L_DIM * K_CLS;     // 16 partial row sums x 32 batches
    float* rsinv = ps  + 32 * 16 * 1024;         // 1/rowsum, 32 batches
    float* up    = rsinv + 32 * 1024;            // pool partials 64x4x512

    const float inv_sqrt_L = 0.044194173824159216f;  // 1/sqrt(512)

    // 0) X = concat(x_sets, y_sets) -> bf16 ; transpose all weights -> bf16 (1 dispatch)
    build_xb<<<dim3((unsigned)(M * D_IN / 256)), 256, 0, stream>>>(xs, ys, Xb);
    {
        TW tw { Wq1, Wk1, Wv1, Wq2, Wk2, Wq1T, Wk1T, Wv1T, Wq2T, Wk2T };
        transpose_all<<<dim3(3584), 256, 0, stream>>>(tw);
    }

    // 1) layer-1 QKV: q1->B1, k1->B2 (normal), v1->B3 TRANSPOSED per batch [512][1024]
    {
        dim3 g(L_DIM / 128, S_LEN / 128, NB);
        gemm_mfma<false, false, true, false, false><<<g, 256, 0, stream>>>(Xb, Wq1T, bq1, B1, D_IN, (long)S_LEN * D_IN, 0, SL, L_DIM, 1.f, nullptr, nullptr);
        gemm_mfma<false, false, true, false, false><<<g, 256, 0, stream>>>(Xb, Wk1T, bk1, B2, D_IN, (long)S_LEN * D_IN, 0, SL, L_DIM, 1.f, nullptr, nullptr);
        gemm_mfma<true,  false, true, false, false><<<g, 256, 0, stream>>>(Xb, Wv1T, bv1, B3, D_IN, (long)S_LEN * D_IN, 0, SL, S_LEN, 1.f, nullptr, nullptr);
    }
    // 2) layer-1 attention, chunked: Ptilde=exp(scores) -> rowsum -> h = relu((P@v)/l) -> B1
    for (int c = 0; c < NB / BCH; ++c) {
        const long aoff = (long)c * BCH * SL;
        dim3 gs(S_LEN / 128, S_LEN / 128, BCH);
        gemm_mfma<false, false, false, true, false><<<gs, 256, 0, stream>>>(
            B1 + aoff, B2 + aoff, nullptr, Scb, L_DIM, SL, SL, SS, S_LEN, inv_sqrt_L, ps, nullptr);
        rowsum_inv<<<dim3((unsigned)(BCH * S_LEN / 256)), 256, 0, stream>>>(ps, rsinv, BCH * S_LEN);
        dim3 gp(L_DIM / 128, S_LEN / 128, BCH);
        gemm_mfma<false, true, false, false, true><<<gp, 256, 0, stream>>>(
            Scb, B3 + aoff, nullptr, B1 + aoff, S_LEN, SS, SL, SL, L_DIM, 1.f, nullptr, rsinv);
    }
    // 3) layer-2 Q,K from h (B1): q2->B2, k2->B3 (v2 eliminated by linearity)
    {
        dim3 g(L_DIM / 128, S_LEN / 128, NB);
        gemm_mfma<false, false, true, false, false><<<g, 256, 0, stream>>>(B1, Wq2T, bq2, B2, L_DIM, SL, 0, SL, L_DIM, 1.f, nullptr, nullptr);
        gemm_mfma<false, false, true, false, false><<<g, 256, 0, stream>>>(B1, Wk2T, bk2, B3, L_DIM, SL, 0, SL, L_DIM, 1.f, nullptr, nullptr);
    }
    // 4) layer-2 attention, chunked: Ptilde -> rowsum -> w = colsum(P * rsinv)
    for (int c = 0; c < NB / BCH; ++c) {
        const long aoff = (long)c * BCH * SL;
        dim3 gs(S_LEN / 128, S_LEN / 128, BCH);
        gemm_mfma<false, false, false, true, false><<<gs, 256, 0, stream>>>(
            B2 + aoff, B3 + aoff, nullptr, Scb, L_DIM, SL, SL, SS, S_LEN, inv_sqrt_L, ps, nullptr);
        rowsum_inv<<<dim3((unsigned)(BCH * S_LEN / 256)), 256, 0, stream>>>(ps, rsinv, BCH * S_LEN);
        colsum_scaled<<<dim3(S_LEN / 256, BCH), 256, 0, stream>>>(Scb, rsinv, w, c, BCH);
    }
    // 5) u = (w/S) @ h  (parallel partials + reduce)
    pool_u_part<<<dim3(NB, 4), 256, 0, stream>>>(B1, w, up);
    pool_u_red<<<dim3(NB * L_DIM / 256), 256, 0, stream>>>(up, u);
    // 6) phi = relu(u @ Wv2 + bv2)   (64 x 512, K=512)
    gemm_f32s<true><<<dim3(L_DIM / TILE, 1), 256, 0, stream>>>(u, Wv2, bv2, phi, NB, L_DIM, L_DIM);
    // 7) logits = phi @ We + be      (64 x 5120, K=512)
    gemm_f32s<false><<<dim3((L_DIM * K_CLS) / TILE, 1), 256, 0, stream>>>(phi, We, be, lg, NB, L_DIM * K_CLS, L_DIM);
    // 8) log_softmax over K=10
    log_softmax10<<<dim3((NB * L_DIM + 255) / 256), 256, 0, stream>>>(lg, out);
}